// Round 20
// baseline (196.728 us; speedup 1.0000x reference)
//
#include <hip/hip_runtime.h>

typedef unsigned short u16;
typedef __attribute__((ext_vector_type(4))) float f32x4;
typedef __attribute__((ext_vector_type(16))) float f32x16;
typedef __attribute__((ext_vector_type(8))) short bf16x8;
typedef __attribute__((ext_vector_type(4))) u16 u16x4;
typedef __attribute__((ext_vector_type(8))) u16 u16x8;

#define MFMA16(a, b, c) __builtin_amdgcn_mfma_f32_16x16x32_bf16((a), (b), (c), 0, 0, 0)
#define MFMA32(a, b, c) __builtin_amdgcn_mfma_f32_32x32x16_bf16((a), (b), (c), 0, 0, 0)

__device__ __forceinline__ u16 f2bf(float f) {
  union { float f; unsigned u; } x; x.f = f;
  unsigned r = x.u + 0x7fffu + ((x.u >> 16) & 1u);  // RNE
  return (u16)(r >> 16);
}

__device__ __forceinline__ unsigned cvtpk(float lo, float hi) {
  unsigned r;
  asm("v_cvt_pk_bf16_f32 %0, %1, %2" : "=v"(r) : "v"(lo), "v"(hi));
  return r;
}

__device__ __forceinline__ void gl_lds16(const void* g, void* l) {
  __builtin_amdgcn_global_load_lds((const __attribute__((address_space(1))) void*)g,
                                   (__attribute__((address_space(3))) void*)l,
                                   16, 0, 0);
}

// ---------------------------------------------------------------- prep: W [K][N] fp32 -> W^T [N][K] bf16
__global__ __launch_bounds__(256) void cvtT_k(const float* __restrict__ W0, const float* __restrict__ W1,
                                              const float* __restrict__ W2, const float* __restrict__ W3,
                                              u16* __restrict__ T0, u16* __restrict__ T1,
                                              u16* __restrict__ T2, u16* __restrict__ T3) {
  __shared__ u16 t[64][72];
  const float* W; u16* T;
  switch (blockIdx.z) {
    case 0: W = W0; T = T0; break;
    case 1: W = W1; T = T1; break;
    case 2: W = W2; T = T2; break;
    default: W = W3; T = T3; break;
  }
  const int tid = threadIdx.x;
  const int tr = blockIdx.x, tc = blockIdx.y;
#pragma unroll
  for (int i = 0; i < 4; ++i) {
    int row = i * 16 + (tid >> 4);
    int c4 = tid & 15;
    float4 v = *(const float4*)&W[(size_t)(tr * 64 + row) * 1024 + tc * 64 + c4 * 4];
    t[row][c4 * 4 + 0] = f2bf(v.x);
    t[row][c4 * 4 + 1] = f2bf(v.y);
    t[row][c4 * 4 + 2] = f2bf(v.z);
    t[row][c4 * 4 + 3] = f2bf(v.w);
  }
  __syncthreads();
#pragma unroll
  for (int i = 0; i < 4; ++i) {
    int orow = i * 16 + (tid >> 4);
    int occ = tid & 15;
    u16x4 o;
#pragma unroll
    for (int j = 0; j < 4; ++j) o[j] = t[occ * 4 + j][orow];
    *(u16x4*)&T[(size_t)(tc * 64 + orow) * 1024 + tr * 64 + occ * 4] = o;
  }
}

// ---------------------------------------------------------------- fused QKV projection GEMM
// R16 champion structure; R20 change: sched_barrier(0) removed from BODY so the compiler can
// interleave next-tile load issue with this tile's ds_read/MFMA stream (loads still land
// 2 iterations ahead; correctness carried by lgkmcnt(0) + s_barrier + implicit va vmcnt).
__global__ __launch_bounds__(512) void gemm_qkv_k(const float* __restrict__ Xq, const float* __restrict__ Xk,
                                                  const float* __restrict__ Xv, const u16* __restrict__ WTb,
                                                  const float* __restrict__ bq, const float* __restrict__ bk,
                                                  const float* __restrict__ bv,
                                                  u16* __restrict__ Qh, u16* __restrict__ Kh,
                                                  u16* __restrict__ Vt, float qscale) {
  __shared__ u16 As[2][128 * 64];   // 32KB
  __shared__ u16 Bs[3][128 * 64];   // 48KB
  const int tid = threadIdx.x;
  const int lane = tid & 63;
  const int w = tid >> 6;                 // 0..7
  const int which = blockIdx.y >> 3;
  const int m0 = blockIdx.x * 128;
  const int n0 = (blockIdx.y & 7) * 128;
  const float* X = which == 0 ? Xq : (which == 1 ? Xk : Xv);
  const u16* WT = WTb + (size_t)which * 1024 * 1024;
  const float* bias = which == 0 ? bq : (which == 1 ? bk : bv);
  const int wr = (w >> 2) * 64;           // 2 row-groups of waves
  const int wc = (w & 3) * 32;            // 4 col-groups
  const int l15 = lane & 15, l4 = lane >> 4, l7 = lane & 7;
  const int sr = lane >> 3;
  const int sc8 = ((lane & 7) ^ sr) * 8;  // pre-swizzled B source chunk (rule 21)
  const int arow = tid >> 3;              // 0..63 (rows arow, 64+arow)
  const int ac = tid & 7;                 // chunk 0..7
  const int aswz = (ac ^ (arow & 7)) * 8; // swizzled u16 chunk offset
  f32x4 acc[4][2] = {};
  float4 va_a[4], va_b[4];

#define BSTAGE(slot_, ks_) do {                                                              \
    int k0_ = (ks_) * 64;                                                                    \
    gl_lds16(WT + (size_t)(n0 + w * 16 + sr) * 1024 + k0_ + sc8, &Bs[slot_][(w * 16) * 64]);       \
    gl_lds16(WT + (size_t)(n0 + w * 16 + 8 + sr) * 1024 + k0_ + sc8, &Bs[slot_][(w * 16 + 8) * 64]); \
  } while (0)

#define ALOAD(VA, ks_) do {                                                                  \
    int k0_ = (ks_) * 64;                                                                    \
    VA[0] = *(const float4*)&X[(size_t)(m0 + arow) * 1024 + k0_ + ac * 8];                   \
    VA[1] = *(const float4*)&X[(size_t)(m0 + arow) * 1024 + k0_ + ac * 8 + 4];               \
    VA[2] = *(const float4*)&X[(size_t)(m0 + 64 + arow) * 1024 + k0_ + ac * 8];              \
    VA[3] = *(const float4*)&X[(size_t)(m0 + 64 + arow) * 1024 + k0_ + ac * 8 + 4];          \
  } while (0)

#define AWRITE(VA, slot_) do {                                                               \
    _Pragma("unroll")                                                                        \
    for (int i_ = 0; i_ < 2; ++i_) {                                                         \
      int row_ = i_ * 64 + arow;                                                             \
      const float4 vlo = VA[2 * i_], vhi = VA[2 * i_ + 1];                                   \
      union { unsigned u[4]; u16x8 v; } o_;                                                  \
      o_.u[0] = cvtpk(vlo.x, vlo.y); o_.u[1] = cvtpk(vlo.z, vlo.w);                          \
      o_.u[2] = cvtpk(vhi.x, vhi.y); o_.u[3] = cvtpk(vhi.z, vhi.w);                          \
      *(u16x8*)&As[slot_][row_ * 64 + aswz] = o_.v;                                          \
    }                                                                                        \
  } while (0)

#define COMPUTE(aslot_, bslot_) do {                                                         \
    const u16* Ac_ = As[aslot_];                                                             \
    const u16* Bc_ = Bs[bslot_];                                                             \
    _Pragma("unroll")                                                                        \
    for (int kk = 0; kk < 2; ++kk) {                                                         \
      int cs_ = ((kk * 4 + l4) ^ l7) * 8;                                                    \
      bf16x8 a_[4], b_[2];                                                                   \
      _Pragma("unroll")                                                                      \
      for (int t = 0; t < 4; ++t)                                                            \
        a_[t] = *(const bf16x8*)&Ac_[(wr + t * 16 + l15) * 64 + cs_];                        \
      _Pragma("unroll")                                                                      \
      for (int u = 0; u < 2; ++u)                                                            \
        b_[u] = *(const bf16x8*)&Bc_[(wc + u * 16 + l15) * 64 + cs_];                        \
      _Pragma("unroll")                                                                      \
      for (int mi = 0; mi < 4; ++mi)                                                         \
        _Pragma("unroll")                                                                    \
        for (int ni = 0; ni < 2; ++ni)                                                       \
          acc[mi][ni] = MFMA16(a_[mi], b_[ni], acc[mi][ni]);                                 \
    }                                                                                        \
  } while (0)

#define BODY(ks_, VA, DO_NEXT) do {                                                          \
    AWRITE(VA, (ks_) & 1);                                                                   \
    asm volatile("s_waitcnt lgkmcnt(0)" ::: "memory");                                       \
    __builtin_amdgcn_s_barrier();                                                            \
    if (DO_NEXT) { BSTAGE(((ks_) + 2) % 3, (ks_) + 2); ALOAD(VA, (ks_) + 2); }               \
    COMPUTE((ks_) & 1, (ks_) % 3);                                                           \
  } while (0)

  BSTAGE(0, 0);
  BSTAGE(1, 1);
  ALOAD(va_a, 0);
  ALOAD(va_b, 1);

  for (int i = 0; i < 7; ++i) {
    BODY(2 * i, va_a, 1);
    BODY(2 * i + 1, va_b, 1);
  }
  BODY(14, va_a, 0);
  BODY(15, va_b, 0);

#undef BSTAGE
#undef ALOAD
#undef AWRITE
#undef COMPUTE
#undef BODY

  const int lr = (lane >> 4) * 4;
  const int lc = lane & 15;
  if (which <= 1) {
    u16* ob = which == 0 ? Qh : Kh;
    float scale = which == 0 ? qscale : 1.0f;
#pragma unroll
    for (int mi = 0; mi < 4; ++mi)
#pragma unroll
      for (int ni = 0; ni < 2; ++ni) {
        int n = n0 + wc + ni * 16 + lc;
        float bb = bias[n];
        int h = n >> 6, d = n & 63;
#pragma unroll
        for (int r = 0; r < 4; ++r) {
          int m = m0 + wr + mi * 16 + lr + r;
          int b = m >> 11, s = m & 2047;
          ob[(((size_t)(b * 16 + h) * 2048 + s) << 6) + d] = f2bf((acc[mi][ni][r] + bb) * scale);
        }
      }
  } else {
#pragma unroll
    for (int mi = 0; mi < 4; ++mi)
#pragma unroll
      for (int ni = 0; ni < 2; ++ni) {
        int n = n0 + wc + ni * 16 + lc;
        float bb = bias[n];
        int h = n >> 6, d = n & 63;
        int m = m0 + wr + mi * 16 + lr;
        int b = m >> 11, s = m & 2047;
        u16x4 pk;
#pragma unroll
        for (int r = 0; r < 4; ++r) pk[r] = f2bf(acc[mi][ni][r] + bb);
        *(u16x4*)&Vt[((size_t)(b * 16 + h) * 64 + d) * 2048 + s] = pk;
      }
  }
}

// ---------------------------------------------------------------- output projection GEMM (fp32 out + bias)
// XOR-swizzled layout via pre-swizzled gl_lds sources; 2-barrier structure. (frozen)
__global__ __launch_bounds__(256) void gemm_o_k(const u16* __restrict__ X, const u16* __restrict__ WT,
                                                const float* __restrict__ bias, float* __restrict__ out) {
  __shared__ u16 As[128 * 64];
  __shared__ u16 Bs[128 * 64];
  const int tid = threadIdx.x;
  const int lane = tid & 63;
  const int w = tid >> 6;                 // 0..3
  const int m0 = blockIdx.x * 128;
  const int n0 = blockIdx.y * 128;
  const int wr = (w >> 1) * 64;
  const int wc = (w & 1) * 64;
  const int l15 = lane & 15, l4 = lane >> 4, l7 = lane & 7;
  const int sr = lane >> 3;
  const int sc8 = ((lane & 7) ^ sr) * 8;
  f32x4 acc[4][4] = {};

  for (int ks = 0; ks < 16; ++ks) {
    const int k0 = ks * 64;
#pragma unroll
    for (int j = 0; j < 4; ++j) {
      int rb = w * 32 + j * 8;
      gl_lds16(X + (size_t)(m0 + rb + sr) * 1024 + k0 + sc8, &As[rb * 64]);
      gl_lds16(WT + (size_t)(n0 + rb + sr) * 1024 + k0 + sc8, &Bs[rb * 64]);
    }
    __syncthreads();
#pragma unroll
    for (int kk = 0; kk < 2; ++kk) {
      int cs = ((kk * 4 + l4) ^ l7) * 8;
      bf16x8 a[4], b[4];
#pragma unroll
      for (int t = 0; t < 4; ++t) {
        a[t] = *(const bf16x8*)&As[(wr + t * 16 + l15) * 64 + cs];
        b[t] = *(const bf16x8*)&Bs[(wc + t * 16 + l15) * 64 + cs];
      }
#pragma unroll
      for (int mi = 0; mi < 4; ++mi)
#pragma unroll
        for (int ni = 0; ni < 4; ++ni)
          acc[mi][ni] = MFMA16(a[mi], b[ni], acc[mi][ni]);
    }
    __syncthreads();
  }

  const int lr = (lane >> 4) * 4;
  const int lc = lane & 15;
#pragma unroll
  for (int mi = 0; mi < 4; ++mi)
#pragma unroll
    for (int ni = 0; ni < 4; ++ni) {
      int n = n0 + wc + ni * 16 + lc;
      float bb = bias[n];
#pragma unroll
      for (int r = 0; r < 4; ++r) {
        int m = m0 + wr + mi * 16 + lr + r;
        out[(size_t)m * 1024 + n] = acc[mi][ni][r] + bb;
      }
    }
}

// ---------------------------------------------------------------- flash attention (R10 structure, frozen)
__global__ __launch_bounds__(512) void attn_k(const u16* __restrict__ Qh, const u16* __restrict__ Kh,
                                              const u16* __restrict__ Vt, u16* __restrict__ AO) {
  __shared__ u16 SMEM[4 * 8192];  // 64KB: slot s = [K 8 frag-blks x 512][V 8 frag-blks x 512]
  const int lane = threadIdx.x & 63, w = threadIdx.x >> 6;  // w: 0..7
  const int hi = lane >> 5, q = lane & 31;

  const int id = blockIdx.x;
  const int bh = ((id >> 3) & 7) * 8 + (id & 7);
  const int qt = id >> 6;
  const int q0 = qt * 256 + w * 32;

  const u16* Qb = Qh + (size_t)bh * 2048 * 64;
  const u16* Kb = Kh + (size_t)bh * 2048 * 64;
  const u16* Vb = Vt + (size_t)bh * 64 * 2048;

  bf16x8 qf[4];
#pragma unroll
  for (int c = 0; c < 4; ++c)
    qf[c] = *(const bf16x8*)&Qb[(size_t)(q0 + q) * 64 + c * 16 + hi * 8];

  bf16x8 onesf;
#pragma unroll
  for (int i = 0; i < 8; ++i) onesf[i] = (short)0x3F80;  // bf16 1.0

  f32x16 o0 = {}, o1 = {}, ol = {};
  const int lo8 = lane * 8;

  const int srowK = (w & 1) * 32 + q;
  const int sck = ((w >> 1) * 2 + hi) * 8;

#define STAGE(slot_, kt_) do {                                                       \
    int k0_ = (kt_) * 64;                                                            \
    gl_lds16(Kb + (size_t)(k0_ + srowK) * 64 + sck, &SMEM[(slot_) * 8192 + w * 512]);          \
    gl_lds16(Vb + (size_t)srowK * 2048 + k0_ + sck, &SMEM[(slot_) * 8192 + 4096 + w * 512]);   \
  } while (0)

  STAGE(0, 0);
  STAGE(1, 1);
  STAGE(2, 2);

  for (int kt = 0; kt < 32; ++kt) {
    if (kt < 30)       asm volatile("s_waitcnt vmcnt(4)" ::: "memory");
    else if (kt == 30) asm volatile("s_waitcnt vmcnt(2)" ::: "memory");
    else               asm volatile("s_waitcnt vmcnt(0)" ::: "memory");
    __builtin_amdgcn_s_barrier();  // releases tile kt AND proves slot (kt-1)&3 free
    if (kt <= 28) STAGE((kt + 3) & 3, kt + 3);
    __builtin_amdgcn_sched_barrier(0);

    const u16* Kc = &SMEM[(kt & 3) * 8192];
    const u16* Vc = Kc + 4096;

    f32x16 s0 = {}, s1 = {};
    __builtin_amdgcn_s_setprio(1);
#pragma unroll
    for (int c = 0; c < 4; ++c) {
      bf16x8 k0 = *(const bf16x8*)&Kc[(c * 2) * 512 + lo8];
      bf16x8 k1 = *(const bf16x8*)&Kc[(c * 2 + 1) * 512 + lo8];
      s0 = MFMA32(k0, qf[c], s0);
      s1 = MFMA32(k1, qf[c], s1);
    }
    __builtin_amdgcn_s_setprio(0);

#pragma unroll
    for (int i = 0; i < 16; ++i) {
      s0[i] = __builtin_exp2f(s0[i]);
      s1[i] = __builtin_exp2f(s1[i]);
    }

    __builtin_amdgcn_s_setprio(1);
#pragma unroll
    for (int t = 0; t < 4; ++t) {
      unsigned wA, wB, wC, wD;
      if (t == 0) { wA = cvtpk(s0[0], s0[1]); wB = cvtpk(s0[2], s0[3]); wC = cvtpk(s0[4], s0[5]); wD = cvtpk(s0[6], s0[7]); }
      else if (t == 1) { wA = cvtpk(s0[8], s0[9]); wB = cvtpk(s0[10], s0[11]); wC = cvtpk(s0[12], s0[13]); wD = cvtpk(s0[14], s0[15]); }
      else if (t == 2) { wA = cvtpk(s1[0], s1[1]); wB = cvtpk(s1[2], s1[3]); wC = cvtpk(s1[4], s1[5]); wD = cvtpk(s1[6], s1[7]); }
      else { wA = cvtpk(s1[8], s1[9]); wB = cvtpk(s1[10], s1[11]); wC = cvtpk(s1[12], s1[13]); wD = cvtpk(s1[14], s1[15]); }
      asm("v_permlane32_swap_b32 %0, %1" : "+v"(wA), "+v"(wC));
      asm("v_permlane32_swap_b32 %0, %1" : "+v"(wB), "+v"(wD));
      union { unsigned u[4]; bf16x8 v; } pf;
      pf.u[0] = wA; pf.u[1] = wB; pf.u[2] = wC; pf.u[3] = wD;
      bf16x8 v0 = *(const bf16x8*)&Vc[(t * 2) * 512 + lo8];
      bf16x8 v1 = *(const bf16x8*)&Vc[(t * 2 + 1) * 512 + lo8];
      o0 = MFMA32(v0, pf.v, o0);
      o1 = MFMA32(v1, pf.v, o1);
      ol = MFMA32(onesf, pf.v, ol);
    }
    __builtin_amdgcn_s_setprio(0);
  }
#undef STAGE

  __builtin_amdgcn_s_barrier();

  float inv = 1.0f / ol[0];
  u16* ep = SMEM + w * 2048;
#pragma unroll
  for (int g = 0; g < 2; ++g) {
    const f32x16 oo = g ? o1 : o0;
#pragma unroll
    for (int j = 0; j < 8; ++j) {
      int d = g * 32 + (j & 1) * 2 + ((j >> 1) & 1) * 8 + (j >> 2) * 16 + 4 * hi;
      unsigned pw = cvtpk(oo[2 * j] * inv, oo[2 * j + 1] * inv);
      *(unsigned*)&ep[q * 64 + ((d >> 3) ^ (q & 7)) * 8 + (d & 7)] = pw;
    }
  }
  asm volatile("s_waitcnt lgkmcnt(0)" ::: "memory");
  const int b = bh >> 4, h = bh & 15;
#pragma unroll
  for (int i = 0; i < 4; ++i) {
    int r = i * 8 + (lane >> 3), c = lane & 7;
    u16x8 vv = *(const u16x8*)&ep[r * 64 + ((c ^ (r & 7)) * 8)];
    size_t row = (size_t)b * 2048 + q0 + r;
    *(u16x8*)&AO[row * 1024 + h * 64 + c * 8] = vv;
  }
}

// ----------------------------------------------------------------
extern "C" void kernel_launch(void* const* d_in, const int* in_sizes, int n_in,
                              void* d_out, int out_size, void* d_ws, size_t ws_size,
                              hipStream_t stream) {
  const float* q  = (const float*)d_in[0];
  const float* k  = (const float*)d_in[1];
  const float* v  = (const float*)d_in[2];
  const float* Wq = (const float*)d_in[3];
  const float* bq = (const float*)d_in[4];
  const float* Wk = (const float*)d_in[5];
  const float* bk = (const float*)d_in[6];
  const float* Wv = (const float*)d_in[7];
  const float* bv = (const float*)d_in[8];
  const float* Wo = (const float*)d_in[9];
  const float* bo = (const float*)d_in[10];
  float* out = (float*)d_out;

  char* ws = (char*)d_ws;
  const size_t SZX = (size_t)8192 * 1024 * 2;
  const size_t SZW = (size_t)1024 * 1024 * 2;
  u16* AO  = (u16*)(ws);                      // attention output (bf16)
  u16* WTq = (u16*)(ws + 3 * SZX);            // WT[3+1] contiguous: q, k, v, o
  u16* WTk = (u16*)(ws + 3 * SZX + SZW);
  u16* WTv = (u16*)(ws + 3 * SZX + 2 * SZW);
  u16* WTo = (u16*)(ws + 3 * SZX + 3 * SZW);
  u16* Qh  = (u16*)(ws + 3 * SZX + 4 * SZW);
  u16* Kh  = (u16*)(ws + 4 * SZX + 4 * SZW);
  u16* Vt  = (u16*)(ws + 5 * SZX + 4 * SZW);

  cvtT_k<<<dim3(16, 16, 4), dim3(256), 0, stream>>>(Wq, Wk, Wv, Wo, WTq, WTk, WTv, WTo);

  // fp32 inputs read directly; conversion fused into swizzled, depth-2 async A-staging.
  // Q scale folds softmax 1/sqrt(64) AND log2(e) for exp2-domain softmax.
  gemm_qkv_k<<<dim3(64, 24), dim3(512), 0, stream>>>(q, k, v, WTq, bq, bk, bv, Qh, Kh, Vt,
                                                     0.125f * 1.4426950408889634f);

  attn_k<<<dim3(512), dim3(512), 0, stream>>>(Qh, Kh, Vt, AO);

  gemm_o_k<<<dim3(64, 8), dim3(256), 0, stream>>>(AO, WTo, bo, out);
}

// Round 21
// 195.103 us; speedup vs baseline: 1.0083x; 1.0083x over previous
//
#include <hip/hip_runtime.h>

typedef unsigned short u16;
typedef __attribute__((ext_vector_type(4))) float f32x4;
typedef __attribute__((ext_vector_type(16))) float f32x16;
typedef __attribute__((ext_vector_type(8))) short bf16x8;
typedef __attribute__((ext_vector_type(4))) u16 u16x4;
typedef __attribute__((ext_vector_type(8))) u16 u16x8;

#define MFMA16(a, b, c) __builtin_amdgcn_mfma_f32_16x16x32_bf16((a), (b), (c), 0, 0, 0)
#define MFMA32(a, b, c) __builtin_amdgcn_mfma_f32_32x32x16_bf16((a), (b), (c), 0, 0, 0)

__device__ __forceinline__ u16 f2bf(float f) {
  union { float f; unsigned u; } x; x.f = f;
  unsigned r = x.u + 0x7fffu + ((x.u >> 16) & 1u);  // RNE
  return (u16)(r >> 16);
}

__device__ __forceinline__ unsigned cvtpk(float lo, float hi) {
  unsigned r;
  asm("v_cvt_pk_bf16_f32 %0, %1, %2" : "=v"(r) : "v"(lo), "v"(hi));
  return r;
}

__device__ __forceinline__ void gl_lds16(const void* g, void* l) {
  __builtin_amdgcn_global_load_lds((const __attribute__((address_space(1))) void*)g,
                                   (__attribute__((address_space(3))) void*)l,
                                   16, 0, 0);
}

// ---------------------------------------------------------------- prep: W [K][N] fp32 -> W^T [N][K] bf16
__global__ __launch_bounds__(256) void cvtT_k(const float* __restrict__ W0, const float* __restrict__ W1,
                                              const float* __restrict__ W2, const float* __restrict__ W3,
                                              u16* __restrict__ T0, u16* __restrict__ T1,
                                              u16* __restrict__ T2, u16* __restrict__ T3) {
  __shared__ u16 t[64][72];
  const float* W; u16* T;
  switch (blockIdx.z) {
    case 0: W = W0; T = T0; break;
    case 1: W = W1; T = T1; break;
    case 2: W = W2; T = T2; break;
    default: W = W3; T = T3; break;
  }
  const int tid = threadIdx.x;
  const int tr = blockIdx.x, tc = blockIdx.y;
#pragma unroll
  for (int i = 0; i < 4; ++i) {
    int row = i * 16 + (tid >> 4);
    int c4 = tid & 15;
    float4 v = *(const float4*)&W[(size_t)(tr * 64 + row) * 1024 + tc * 64 + c4 * 4];
    t[row][c4 * 4 + 0] = f2bf(v.x);
    t[row][c4 * 4 + 1] = f2bf(v.y);
    t[row][c4 * 4 + 2] = f2bf(v.z);
    t[row][c4 * 4 + 3] = f2bf(v.w);
  }
  __syncthreads();
#pragma unroll
  for (int i = 0; i < 4; ++i) {
    int orow = i * 16 + (tid >> 4);
    int occ = tid & 15;
    u16x4 o;
#pragma unroll
    for (int j = 0; j < 4; ++j) o[j] = t[occ * 4 + j][orow];
    *(u16x4*)&T[(size_t)(tc * 64 + orow) * 1024 + tr * 64 + occ * 4] = o;
  }
}

// ---------------------------------------------------------------- fused QKV projection GEMM (R19 champion + T5)
// XOR-swizzled [128][64] LDS; B via gl_lds w/ pre-swizzled SOURCE in a 3-SLOT ring;
// A coalesced fp32 -> v_cvt_pk_bf16_f32 -> swizzled ds_write_b128; depth-2 A prefetch;
// ONE barrier per K-step; LDS 80KB -> 2 blocks/CU (2 independent barrier groups = role
// diversity). R21: s_setprio(1) around each MFMA cluster (T5; cross-block arbitration).
__global__ __launch_bounds__(512) void gemm_qkv_k(const float* __restrict__ Xq, const float* __restrict__ Xk,
                                                  const float* __restrict__ Xv, const u16* __restrict__ WTb,
                                                  const float* __restrict__ bq, const float* __restrict__ bk,
                                                  const float* __restrict__ bv,
                                                  u16* __restrict__ Qh, u16* __restrict__ Kh,
                                                  u16* __restrict__ Vt, float qscale) {
  __shared__ u16 As[2][128 * 64];   // 32KB
  __shared__ u16 Bs[3][128 * 64];   // 48KB
  const int tid = threadIdx.x;
  const int lane = tid & 63;
  const int w = tid >> 6;                 // 0..7
  const int which = blockIdx.y >> 3;
  const int m0 = blockIdx.x * 128;
  const int n0 = (blockIdx.y & 7) * 128;
  const float* X = which == 0 ? Xq : (which == 1 ? Xk : Xv);
  const u16* WT = WTb + (size_t)which * 1024 * 1024;
  const float* bias = which == 0 ? bq : (which == 1 ? bk : bv);
  const int wr = (w >> 2) * 64;           // 2 row-groups of waves
  const int wc = (w & 3) * 32;            // 4 col-groups
  const int l15 = lane & 15, l4 = lane >> 4, l7 = lane & 7;
  const int sr = lane >> 3;
  const int sc8 = ((lane & 7) ^ sr) * 8;  // pre-swizzled B source chunk (rule 21)
  const int arow = tid >> 3;              // 0..63 (rows arow, 64+arow)
  const int ac = tid & 7;                 // chunk 0..7
  const int aswz = (ac ^ (arow & 7)) * 8; // swizzled u16 chunk offset
  f32x4 acc[4][2] = {};
  float4 va_a[4], va_b[4];

#define BSTAGE(slot_, ks_) do {                                                              \
    int k0_ = (ks_) * 64;                                                                    \
    gl_lds16(WT + (size_t)(n0 + w * 16 + sr) * 1024 + k0_ + sc8, &Bs[slot_][(w * 16) * 64]);       \
    gl_lds16(WT + (size_t)(n0 + w * 16 + 8 + sr) * 1024 + k0_ + sc8, &Bs[slot_][(w * 16 + 8) * 64]); \
  } while (0)

#define ALOAD(VA, ks_) do {                                                                  \
    int k0_ = (ks_) * 64;                                                                    \
    VA[0] = *(const float4*)&X[(size_t)(m0 + arow) * 1024 + k0_ + ac * 8];                   \
    VA[1] = *(const float4*)&X[(size_t)(m0 + arow) * 1024 + k0_ + ac * 8 + 4];               \
    VA[2] = *(const float4*)&X[(size_t)(m0 + 64 + arow) * 1024 + k0_ + ac * 8];              \
    VA[3] = *(const float4*)&X[(size_t)(m0 + 64 + arow) * 1024 + k0_ + ac * 8 + 4];          \
  } while (0)

#define AWRITE(VA, slot_) do {                                                               \
    _Pragma("unroll")                                                                        \
    for (int i_ = 0; i_ < 2; ++i_) {                                                         \
      int row_ = i_ * 64 + arow;                                                             \
      const float4 vlo = VA[2 * i_], vhi = VA[2 * i_ + 1];                                   \
      union { unsigned u[4]; u16x8 v; } o_;                                                  \
      o_.u[0] = cvtpk(vlo.x, vlo.y); o_.u[1] = cvtpk(vlo.z, vlo.w);                          \
      o_.u[2] = cvtpk(vhi.x, vhi.y); o_.u[3] = cvtpk(vhi.z, vhi.w);                          \
      *(u16x8*)&As[slot_][row_ * 64 + aswz] = o_.v;                                          \
    }                                                                                        \
  } while (0)

#define COMPUTE(aslot_, bslot_) do {                                                         \
    const u16* Ac_ = As[aslot_];                                                             \
    const u16* Bc_ = Bs[bslot_];                                                             \
    _Pragma("unroll")                                                                        \
    for (int kk = 0; kk < 2; ++kk) {                                                         \
      int cs_ = ((kk * 4 + l4) ^ l7) * 8;                                                    \
      bf16x8 a_[4], b_[2];                                                                   \
      _Pragma("unroll")                                                                      \
      for (int t = 0; t < 4; ++t)                                                            \
        a_[t] = *(const bf16x8*)&Ac_[(wr + t * 16 + l15) * 64 + cs_];                        \
      _Pragma("unroll")                                                                      \
      for (int u = 0; u < 2; ++u)                                                            \
        b_[u] = *(const bf16x8*)&Bc_[(wc + u * 16 + l15) * 64 + cs_];                        \
      __builtin_amdgcn_s_setprio(1);                                                         \
      _Pragma("unroll")                                                                      \
      for (int mi = 0; mi < 4; ++mi)                                                         \
        _Pragma("unroll")                                                                    \
        for (int ni = 0; ni < 2; ++ni)                                                       \
          acc[mi][ni] = MFMA16(a_[mi], b_[ni], acc[mi][ni]);                                 \
      __builtin_amdgcn_s_setprio(0);                                                         \
    }                                                                                        \
  } while (0)

#define BODY(ks_, VA, DO_NEXT) do {                                                          \
    AWRITE(VA, (ks_) & 1);                                                                   \
    asm volatile("s_waitcnt lgkmcnt(0)" ::: "memory");                                       \
    asm volatile("s_waitcnt vmcnt(6)" ::: "memory");  /* B(ks) already retired (issue order) */ \
    __builtin_amdgcn_s_barrier();                                                            \
    if (DO_NEXT) { BSTAGE(((ks_) + 2) % 3, (ks_) + 2); ALOAD(VA, (ks_) + 2); }               \
    __builtin_amdgcn_sched_barrier(0);                                                       \
    COMPUTE((ks_) & 1, (ks_) % 3);                                                           \
  } while (0)

  BSTAGE(0, 0);
  BSTAGE(1, 1);
  ALOAD(va_a, 0);
  ALOAD(va_b, 1);

  for (int i = 0; i < 7; ++i) {
    BODY(2 * i, va_a, 1);
    BODY(2 * i + 1, va_b, 1);
  }
  BODY(14, va_a, 0);
  BODY(15, va_b, 0);

#undef BSTAGE
#undef ALOAD
#undef AWRITE
#undef COMPUTE
#undef BODY

  const int lr = (lane >> 4) * 4;
  const int lc = lane & 15;
  if (which <= 1) {
    u16* ob = which == 0 ? Qh : Kh;
    float scale = which == 0 ? qscale : 1.0f;
#pragma unroll
    for (int mi = 0; mi < 4; ++mi)
#pragma unroll
      for (int ni = 0; ni < 2; ++ni) {
        int n = n0 + wc + ni * 16 + lc;
        float bb = bias[n];
        int h = n >> 6, d = n & 63;
#pragma unroll
        for (int r = 0; r < 4; ++r) {
          int m = m0 + wr + mi * 16 + lr + r;
          int b = m >> 11, s = m & 2047;
          ob[(((size_t)(b * 16 + h) * 2048 + s) << 6) + d] = f2bf((acc[mi][ni][r] + bb) * scale);
        }
      }
  } else {
#pragma unroll
    for (int mi = 0; mi < 4; ++mi)
#pragma unroll
      for (int ni = 0; ni < 2; ++ni) {
        int n = n0 + wc + ni * 16 + lc;
        float bb = bias[n];
        int h = n >> 6, d = n & 63;
        int m = m0 + wr + mi * 16 + lr;
        int b = m >> 11, s = m & 2047;
        u16x4 pk;
#pragma unroll
        for (int r = 0; r < 4; ++r) pk[r] = f2bf(acc[mi][ni][r] + bb);
        *(u16x4*)&Vt[((size_t)(b * 16 + h) * 64 + d) * 2048 + s] = pk;
      }
  }
}

// ---------------------------------------------------------------- output projection GEMM (fp32 out + bias)
// XOR-swizzled layout via pre-swizzled gl_lds sources; 2-barrier structure. (frozen)
__global__ __launch_bounds__(256) void gemm_o_k(const u16* __restrict__ X, const u16* __restrict__ WT,
                                                const float* __restrict__ bias, float* __restrict__ out) {
  __shared__ u16 As[128 * 64];
  __shared__ u16 Bs[128 * 64];
  const int tid = threadIdx.x;
  const int lane = tid & 63;
  const int w = tid >> 6;                 // 0..3
  const int m0 = blockIdx.x * 128;
  const int n0 = blockIdx.y * 128;
  const int wr = (w >> 1) * 64;
  const int wc = (w & 1) * 64;
  const int l15 = lane & 15, l4 = lane >> 4, l7 = lane & 7;
  const int sr = lane >> 3;
  const int sc8 = ((lane & 7) ^ sr) * 8;
  f32x4 acc[4][4] = {};

  for (int ks = 0; ks < 16; ++ks) {
    const int k0 = ks * 64;
#pragma unroll
    for (int j = 0; j < 4; ++j) {
      int rb = w * 32 + j * 8;
      gl_lds16(X + (size_t)(m0 + rb + sr) * 1024 + k0 + sc8, &As[rb * 64]);
      gl_lds16(WT + (size_t)(n0 + rb + sr) * 1024 + k0 + sc8, &Bs[rb * 64]);
    }
    __syncthreads();
#pragma unroll
    for (int kk = 0; kk < 2; ++kk) {
      int cs = ((kk * 4 + l4) ^ l7) * 8;
      bf16x8 a[4], b[4];
#pragma unroll
      for (int t = 0; t < 4; ++t) {
        a[t] = *(const bf16x8*)&As[(wr + t * 16 + l15) * 64 + cs];
        b[t] = *(const bf16x8*)&Bs[(wc + t * 16 + l15) * 64 + cs];
      }
#pragma unroll
      for (int mi = 0; mi < 4; ++mi)
#pragma unroll
        for (int ni = 0; ni < 4; ++ni)
          acc[mi][ni] = MFMA16(a[mi], b[ni], acc[mi][ni]);
    }
    __syncthreads();
  }

  const int lr = (lane >> 4) * 4;
  const int lc = lane & 15;
#pragma unroll
  for (int mi = 0; mi < 4; ++mi)
#pragma unroll
    for (int ni = 0; ni < 4; ++ni) {
      int n = n0 + wc + ni * 16 + lc;
      float bb = bias[n];
#pragma unroll
      for (int r = 0; r < 4; ++r) {
        int m = m0 + wr + mi * 16 + lr + r;
        out[(size_t)m * 1024 + n] = acc[mi][ni][r] + bb;
      }
    }
}

// ---------------------------------------------------------------- flash attention (R10 structure, frozen)
__global__ __launch_bounds__(512) void attn_k(const u16* __restrict__ Qh, const u16* __restrict__ Kh,
                                              const u16* __restrict__ Vt, u16* __restrict__ AO) {
  __shared__ u16 SMEM[4 * 8192];  // 64KB: slot s = [K 8 frag-blks x 512][V 8 frag-blks x 512]
  const int lane = threadIdx.x & 63, w = threadIdx.x >> 6;  // w: 0..7
  const int hi = lane >> 5, q = lane & 31;

  const int id = blockIdx.x;
  const int bh = ((id >> 3) & 7) * 8 + (id & 7);
  const int qt = id >> 6;
  const int q0 = qt * 256 + w * 32;

  const u16* Qb = Qh + (size_t)bh * 2048 * 64;
  const u16* Kb = Kh + (size_t)bh * 2048 * 64;
  const u16* Vb = Vt + (size_t)bh * 64 * 2048;

  bf16x8 qf[4];
#pragma unroll
  for (int c = 0; c < 4; ++c)
    qf[c] = *(const bf16x8*)&Qb[(size_t)(q0 + q) * 64 + c * 16 + hi * 8];

  bf16x8 onesf;
#pragma unroll
  for (int i = 0; i < 8; ++i) onesf[i] = (short)0x3F80;  // bf16 1.0

  f32x16 o0 = {}, o1 = {}, ol = {};
  const int lo8 = lane * 8;

  const int srowK = (w & 1) * 32 + q;
  const int sck = ((w >> 1) * 2 + hi) * 8;

#define STAGE(slot_, kt_) do {                                                       \
    int k0_ = (kt_) * 64;                                                            \
    gl_lds16(Kb + (size_t)(k0_ + srowK) * 64 + sck, &SMEM[(slot_) * 8192 + w * 512]);          \
    gl_lds16(Vb + (size_t)srowK * 2048 + k0_ + sck, &SMEM[(slot_) * 8192 + 4096 + w * 512]);   \
  } while (0)

  STAGE(0, 0);
  STAGE(1, 1);
  STAGE(2, 2);

  for (int kt = 0; kt < 32; ++kt) {
    if (kt < 30)       asm volatile("s_waitcnt vmcnt(4)" ::: "memory");
    else if (kt == 30) asm volatile("s_waitcnt vmcnt(2)" ::: "memory");
    else               asm volatile("s_waitcnt vmcnt(0)" ::: "memory");
    __builtin_amdgcn_s_barrier();  // releases tile kt AND proves slot (kt-1)&3 free
    if (kt <= 28) STAGE((kt + 3) & 3, kt + 3);
    __builtin_amdgcn_sched_barrier(0);

    const u16* Kc = &SMEM[(kt & 3) * 8192];
    const u16* Vc = Kc + 4096;

    f32x16 s0 = {}, s1 = {};
    __builtin_amdgcn_s_setprio(1);
#pragma unroll
    for (int c = 0; c < 4; ++c) {
      bf16x8 k0 = *(const bf16x8*)&Kc[(c * 2) * 512 + lo8];
      bf16x8 k1 = *(const bf16x8*)&Kc[(c * 2 + 1) * 512 + lo8];
      s0 = MFMA32(k0, qf[c], s0);
      s1 = MFMA32(k1, qf[c], s1);
    }
    __builtin_amdgcn_s_setprio(0);

#pragma unroll
    for (int i = 0; i < 16; ++i) {
      s0[i] = __builtin_exp2f(s0[i]);
      s1[i] = __builtin_exp2f(s1[i]);
    }

    __builtin_amdgcn_s_setprio(1);
#pragma unroll
    for (int t = 0; t < 4; ++t) {
      unsigned wA, wB, wC, wD;
      if (t == 0) { wA = cvtpk(s0[0], s0[1]); wB = cvtpk(s0[2], s0[3]); wC = cvtpk(s0[4], s0[5]); wD = cvtpk(s0[6], s0[7]); }
      else if (t == 1) { wA = cvtpk(s0[8], s0[9]); wB = cvtpk(s0[10], s0[11]); wC = cvtpk(s0[12], s0[13]); wD = cvtpk(s0[14], s0[15]); }
      else if (t == 2) { wA = cvtpk(s1[0], s1[1]); wB = cvtpk(s1[2], s1[3]); wC = cvtpk(s1[4], s1[5]); wD = cvtpk(s1[6], s1[7]); }
      else { wA = cvtpk(s1[8], s1[9]); wB = cvtpk(s1[10], s1[11]); wC = cvtpk(s1[12], s1[13]); wD = cvtpk(s1[14], s1[15]); }
      asm("v_permlane32_swap_b32 %0, %1" : "+v"(wA), "+v"(wC));
      asm("v_permlane32_swap_b32 %0, %1" : "+v"(wB), "+v"(wD));
      union { unsigned u[4]; bf16x8 v; } pf;
      pf.u[0] = wA; pf.u[1] = wB; pf.u[2] = wC; pf.u[3] = wD;
      bf16x8 v0 = *(const bf16x8*)&Vc[(t * 2) * 512 + lo8];
      bf16x8 v1 = *(const bf16x8*)&Vc[(t * 2 + 1) * 512 + lo8];
      o0 = MFMA32(v0, pf.v, o0);
      o1 = MFMA32(v1, pf.v, o1);
      ol = MFMA32(onesf, pf.v, ol);
    }
    __builtin_amdgcn_s_setprio(0);
  }
#undef STAGE

  __builtin_amdgcn_s_barrier();

  float inv = 1.0f / ol[0];
  u16* ep = SMEM + w * 2048;
#pragma unroll
  for (int g = 0; g < 2; ++g) {
    const f32x16 oo = g ? o1 : o0;
#pragma unroll
    for (int j = 0; j < 8; ++j) {
      int d = g * 32 + (j & 1) * 2 + ((j >> 1) & 1) * 8 + (j >> 2) * 16 + 4 * hi;
      unsigned pw = cvtpk(oo[2 * j] * inv, oo[2 * j + 1] * inv);
      *(unsigned*)&ep[q * 64 + ((d >> 3) ^ (q & 7)) * 8 + (d & 7)] = pw;
    }
  }
  asm volatile("s_waitcnt lgkmcnt(0)" ::: "memory");
  const int b = bh >> 4, h = bh & 15;
#pragma unroll
  for (int i = 0; i < 4; ++i) {
    int r = i * 8 + (lane >> 3), c = lane & 7;
    u16x8 vv = *(const u16x8*)&ep[r * 64 + ((c ^ (r & 7)) * 8)];
    size_t row = (size_t)b * 2048 + q0 + r;
    *(u16x8*)&AO[row * 1024 + h * 64 + c * 8] = vv;
  }
}

// ----------------------------------------------------------------
extern "C" void kernel_launch(void* const* d_in, const int* in_sizes, int n_in,
                              void* d_out, int out_size, void* d_ws, size_t ws_size,
                              hipStream_t stream) {
  const float* q  = (const float*)d_in[0];
  const float* k  = (const float*)d_in[1];
  const float* v  = (const float*)d_in[2];
  const float* Wq = (const float*)d_in[3];
  const float* bq = (const float*)d_in[4];
  const float* Wk = (const float*)d_in[5];
  const float* bk = (const float*)d_in[6];
  const float* Wv = (const float*)d_in[7];
  const float* bv = (const float*)d_in[8];
  const float* Wo = (const float*)d_in[9];
  const float* bo = (const float*)d_in[10];
  float* out = (float*)d_out;

  char* ws = (char*)d_ws;
  const size_t SZX = (size_t)8192 * 1024 * 2;
  const size_t SZW = (size_t)1024 * 1024 * 2;
  u16* AO  = (u16*)(ws);                      // attention output (bf16)
  u16* WTq = (u16*)(ws + 3 * SZX);            // WT[3+1] contiguous: q, k, v, o
  u16* WTk = (u16*)(ws + 3 * SZX + SZW);
  u16* WTv = (u16*)(ws + 3 * SZX + 2 * SZW);
  u16* WTo = (u16*)(ws + 3 * SZX + 3 * SZW);
  u16* Qh  = (u16*)(ws + 3 * SZX + 4 * SZW);
  u16* Kh  = (u16*)(ws + 4 * SZX + 4 * SZW);
  u16* Vt  = (u16*)(ws + 5 * SZX + 4 * SZW);

  cvtT_k<<<dim3(16, 16, 4), dim3(256), 0, stream>>>(Wq, Wk, Wv, Wo, WTq, WTk, WTv, WTo);

  // fp32 inputs read directly; conversion fused into swizzled, depth-2 async A-staging.
  // Q scale folds softmax 1/sqrt(64) AND log2(e) for exp2-domain softmax.
  gemm_qkv_k<<<dim3(64, 24), dim3(512), 0, stream>>>(q, k, v, WTq, bq, bk, bv, Qh, Kh, Vt,
                                                     0.125f * 1.4426950408889634f);

  attn_k<<<dim3(512), dim3(512), 0, stream>>>(Qh, Kh, Vt, AO);

  gemm_o_k<<<dim3(64, 8), dim3(256), 0, stream>>>(AO, WTo, bo, out);
}